// Round 1
// baseline (508.894 us; speedup 1.0000x reference)
//
#include <hip/hip_runtime.h>

// Backward slice from the single output node n-1:
//   D = {n-1} U in-neighbors(n-1) (~34 nodes); layer-2 agg needs only edges
//   into D (~1100); deg needed for their sources U D.
//
// Round-6 restructure (launch-boundary bound; 2x ~45us harness workspace
// poison fills are a fixed floor inside the timed region):
//   5 dispatches -> 4:
//   memset: zero bm1+cnts+s1Dg+deg (~415KB, one fill)
//   passA:  scan dst -> FULL deg histogram (3.2M atomics, makes deg
//           independent of the D-discovery chain) + S1 multiset + bm1/Dlist
//   passB:  scan dst w/ bm1 filter -> accumulate msgs directly into global
//           s1Dg[idx] (deg already final), then last-finishing block
//           (threadfence + ticket) runs the ~34-node layer-1/2 + FC epilogue
//   -> pass3's full 12.8MB dst re-scan and the 1-block k_final dispatch
//      are both eliminated.

#define S1CAP 2048
#define DCAP  192

// cnts: [0]=S1 count, [1]=D count, [2]=passB done-ticket

__global__ __launch_bounds__(256)
void k_passA(const int* __restrict__ src, const int* __restrict__ dst,
             int E4, int E, int n, int* __restrict__ cnts,
             int* __restrict__ S1, unsigned* __restrict__ bm1,
             int* __restrict__ Dlist, int* __restrict__ deg) {
    int i = blockIdx.x * blockDim.x + threadIdx.x;
    const int tgt = n - 1;
    if (i < E4) {
        int4 d4 = ((const int4*)dst)[i];
        int dd[4] = {d4.x, d4.y, d4.z, d4.w};
#pragma unroll
        for (int k = 0; k < 4; ++k) {
            int d = dd[k];
            atomicAdd(&deg[d], 1);          // full in-degree histogram
            if (d == tgt) {
                int s = src[i * 4 + k];
                int p = atomicAdd(&cnts[0], 1);
                if (p < S1CAP) S1[p] = s;
                unsigned bit = 1u << (s & 31);
                unsigned old = atomicOr(&bm1[s >> 5], bit);
                if (!(old & bit)) {
                    int q = atomicAdd(&cnts[1], 1);
                    if (q < DCAP) Dlist[q] = s;
                }
            }
        }
    }
    if (i == 0) {
        for (int e = E4 * 4; e < E; ++e) {
            int d = dst[e];
            atomicAdd(&deg[d], 1);
            if (d == tgt) {
                int s = src[e];
                int p = atomicAdd(&cnts[0], 1);
                if (p < S1CAP) S1[p] = s;
                unsigned bit = 1u << (s & 31);
                unsigned old = atomicOr(&bm1[s >> 5], bit);
                if (!(old & bit)) {
                    int q = atomicAdd(&cnts[1], 1);
                    if (q < DCAP) Dlist[q] = s;
                }
            }
        }
        // tgt itself is in D (self-loop)
        unsigned bit = 1u << (tgt & 31);
        unsigned old = atomicOr(&bm1[tgt >> 5], bit);
        if (!(old & bit)) {
            int q = atomicAdd(&cnts[1], 1);
            if (q < DCAP) Dlist[q] = tgt;
        }
    }
}

__global__ __launch_bounds__(256)
void k_passB(const int* __restrict__ src, const int* __restrict__ dst,
             int E4, int E, int n,
             const unsigned* __restrict__ bm1, const int* __restrict__ deg,
             int* __restrict__ cnts, const int* __restrict__ S1,
             const int* __restrict__ Dlist, float* __restrict__ s1Dg,
             const float* __restrict__ x,
             const float* __restrict__ W1, const float* __restrict__ b1,
             const float* __restrict__ W2, const float* __restrict__ b2,
             const float* __restrict__ Wfc, const float* __restrict__ bfc,
             float* __restrict__ out) {
    __shared__ int sD[DCAP];
    __shared__ int sCntD;
    __shared__ int sLast;
    const int tid = threadIdx.x;
    const int tgt = n - 1;

    if (tid == 0) {
        int c = cnts[1];
        sCntD = c > DCAP ? DCAP : c;
    }
    __syncthreads();
    const int cntD = sCntD;
    for (int q = tid; q < cntD; q += 256) sD[q] = Dlist[q];
    __syncthreads();

    // --- scan phase: edges into D -> message accumulation (deg is final) ---
    int i = blockIdx.x * blockDim.x + tid;
    if (i < E4) {
        int4 d4 = ((const int4*)dst)[i];
        int dd[4] = {d4.x, d4.y, d4.z, d4.w};
#pragma unroll
        for (int k = 0; k < 4; ++k) {
            int d = dd[k];
            if ((bm1[d >> 5] >> (d & 31)) & 1u) {
                int s = src[i * 4 + k];
                float msg = x[s] * rsqrtf((float)(deg[s] + 1));
                int idx = 0;
                for (int q = 0; q < cntD; ++q) { if (sD[q] == d) { idx = q; break; } }
                atomicAdd(&s1Dg[idx], msg);
            }
        }
    }
    if (i == 0) {
        for (int e = E4 * 4; e < E; ++e) {
            int d = dst[e];
            if ((bm1[d >> 5] >> (d & 31)) & 1u) {
                int s = src[e];
                float msg = x[s] * rsqrtf((float)(deg[s] + 1));
                int idx = 0;
                for (int q = 0; q < cntD; ++q) { if (sD[q] == d) { idx = q; break; } }
                atomicAdd(&s1Dg[idx], msg);
            }
        }
    }

    // --- done ticket: last-finishing block runs the epilogue ---
    __threadfence();                         // release: publish s1Dg atomics
    if (tid == 0)
        sLast = (atomicAdd(&cnts[2], 1) == (int)gridDim.x - 1) ? 1 : 0;
    __syncthreads();
    if (!sLast) return;
    __threadfence();                         // acquire side

    // --- epilogue (single block): layer-1 transform, layer-2 agg, FC ---
    __shared__ float gD[DCAP][8];
    __shared__ float sW1[16], sb1[16], sW2[128], agg[8];
    if (tid < 16) { sW1[tid] = W1[tid]; sb1[tid] = b1[tid]; }
    if (tid < 128) sW2[tid] = W2[tid];
    if (tid < 8) agg[tid] = 0.f;
    __syncthreads();

    for (int di = tid; di < cntD; di += 256) {
        int d = sD[di];
        float dv = rsqrtf((float)(deg[d] + 1));
        float t = dv * (s1Dg[di] + x[d] * dv);   // + self-loop term
        float g8[8] = {0, 0, 0, 0, 0, 0, 0, 0};
#pragma unroll
        for (int c = 0; c < 16; ++c) {
            float h1 = fmaxf(fmaf(t, sW1[c], sb1[c]), 0.f);
#pragma unroll
            for (int j = 0; j < 8; ++j) g8[j] = fmaf(h1, sW2[c * 8 + j], g8[j]);
        }
#pragma unroll
        for (int j = 0; j < 8; ++j) gD[di][j] = dv * g8[j];
    }
    __syncthreads();

    int cnt1 = cnts[0]; if (cnt1 > S1CAP) cnt1 = S1CAP;
    for (int idx = tid; idx < cnt1 * 8; idx += 256) {
        int p = idx >> 3, j = idx & 7;
        int s = S1[p];
        int q = 0;
        while (sD[q] != s) ++q;
        atomicAdd(&agg[j], gD[q][j]);
    }
    __syncthreads();

    if (tid == 0) {
        int q = 0;
        while (sD[q] != tgt) ++q;
        float dv = rsqrtf((float)(deg[tgt] + 1));
        float o = 0.f;
#pragma unroll
        for (int j = 0; j < 8; ++j)
            o += fmaxf(fmaf(dv, agg[j] + gD[q][j], b2[j]), 0.f) * Wfc[j];
        out[0] = o + bfc[0];
    }
}

extern "C" void kernel_launch(void* const* d_in, const int* in_sizes, int n_in,
                              void* d_out, int out_size, void* d_ws, size_t ws_size,
                              hipStream_t stream) {
    const float* x   = (const float*)d_in[0];
    const int*   ei  = (const int*)d_in[1];
    const float* W1  = (const float*)d_in[2];
    const float* b1  = (const float*)d_in[3];
    const float* W2  = (const float*)d_in[4];
    const float* b2  = (const float*)d_in[5];
    const float* Wfc = (const float*)d_in[6];
    const float* bfc = (const float*)d_in[7];
    float* out = (float*)d_out;

    int n = in_sizes[0];
    int E = in_sizes[1] / 2;
    const int* src = ei;
    const int* dst = ei + E;

    auto align16 = [](size_t v) { return (v + 15) & ~(size_t)15; };
    size_t bmBytes = align16(((size_t)(n + 31) / 32) * 4);
    char* ws = (char*)d_ws;
    size_t off = 0;
    unsigned* bm1  = (unsigned*)(ws + off); off += bmBytes;
    int*      cnts = (int*)(ws + off);      off += 64;
    float*    s1Dg = (float*)(ws + off);    off += align16(DCAP * 4);
    int*      deg  = (int*)(ws + off);      off += align16((size_t)n * 4);
    size_t zeroBytes = off;                 // bm1 + cnts + s1Dg + deg (~415KB)
    int*      S1    = (int*)(ws + off);     off += S1CAP * 4;
    int*      Dlist = (int*)(ws + off);     off += align16(DCAP * 4);

    hipMemsetAsync(d_ws, 0, zeroBytes, stream);

    int E4 = E >> 2;
    int bE4 = (E4 + 255) / 256;

    k_passA<<<bE4, 256, 0, stream>>>(src, dst, E4, E, n, cnts, S1, bm1, Dlist, deg);
    k_passB<<<bE4, 256, 0, stream>>>(src, dst, E4, E, n, bm1, deg, cnts, S1,
                                     Dlist, s1Dg, x, W1, b1, W2, b2, Wfc, bfc, out);
}

// Round 2
// 188.471 us; speedup vs baseline: 2.7001x; 2.7001x over previous
//
#include <hip/hip_runtime.h>

// Backward slice from the single output node n-1:
//   D = {n-1} U in-neighbors(n-1) (~34 nodes); layer-2 agg needs only edges
//   into D (~1100); deg needed only for their sources U D (~1135 nodes).
//
// Round-7: revert the round-6 regression (full-deg histogram = ~100us of
// scattered device atomics; __threadfence per block = per-XCD L2
// writeback/invalidate storm -> 304us). Keep the round-0 structure but merge
// pass3+final via a LIGHTWEIGHT ticket:
//   - scan phase identical to pass3 (no preamble, no fences)
//   - each wave drains its own atomics (s_waitcnt vmcnt(0), already implied
//     by __syncthreads), then ONE ticket atomic per block
//   - last-finishing block runs the epilogue, reading deg via atomicOr(p,0)
//     (atomics are LLC-coherent; no cache flush needed). Data from earlier
//     kernels (S1/L2/cnts/x) is covered by the launch-boundary acquire.
// Dispatches: memset(25KB) + pass1 + pass2 + pass3f  (5 -> 4).

#define S1CAP 2048
#define DCAP  192
#define L2CAP 65536
#define HASHSZ 512

// cnts: [0]=S1 count, [1]=D count, [2]=L2 count, [3]=pass3f ticket

__global__ __launch_bounds__(256)
void k_pass1(const int* __restrict__ src, const int* __restrict__ dst,
             int E4, int E, int n, int* __restrict__ cnts,
             int* __restrict__ S1, unsigned* __restrict__ bm1,
             int* __restrict__ Dlist) {
    int i = blockIdx.x * blockDim.x + threadIdx.x;
    const int tgt = n - 1;
    if (i < E4) {
        int4 d4 = ((const int4*)dst)[i];
        int dd[4] = {d4.x, d4.y, d4.z, d4.w};
#pragma unroll
        for (int k = 0; k < 4; ++k) {
            if (dd[k] == tgt) {
                int s = src[i * 4 + k];
                int p = atomicAdd(&cnts[0], 1);
                if (p < S1CAP) S1[p] = s;
                unsigned bit = 1u << (s & 31);
                unsigned old = atomicOr(&bm1[s >> 5], bit);
                if (!(old & bit)) {
                    int q = atomicAdd(&cnts[1], 1);
                    if (q < DCAP) Dlist[q] = s;
                }
            }
        }
    }
    if (i == 0) {
        for (int e = E4 * 4; e < E; ++e) {
            if (dst[e] == tgt) {
                int s = src[e];
                int p = atomicAdd(&cnts[0], 1);
                if (p < S1CAP) S1[p] = s;
                unsigned bit = 1u << (s & 31);
                unsigned old = atomicOr(&bm1[s >> 5], bit);
                if (!(old & bit)) {
                    int q = atomicAdd(&cnts[1], 1);
                    if (q < DCAP) Dlist[q] = s;
                }
            }
        }
        // tgt itself is in D (self-loop)
        unsigned bit = 1u << (tgt & 31);
        unsigned old = atomicOr(&bm1[tgt >> 5], bit);
        if (!(old & bit)) {
            int q = atomicAdd(&cnts[1], 1);
            if (q < DCAP) Dlist[q] = tgt;
        }
    }
}

__global__ __launch_bounds__(256)
void k_pass2(const int* __restrict__ src, const int* __restrict__ dst,
             int E4, int E, const unsigned* __restrict__ bm1,
             int* __restrict__ cnts, unsigned long long* __restrict__ L2,
             unsigned* __restrict__ bm2, int* __restrict__ deg,
             const int* __restrict__ Dlist) {
    int i = blockIdx.x * blockDim.x + threadIdx.x;
    // D itself into bm2 (lazy deg zero)
    if (i < DCAP) {
        int cntD = cnts[1]; if (cntD > DCAP) cntD = DCAP;
        if (i < cntD) {
            int d = Dlist[i];
            unsigned bit = 1u << (d & 31);
            unsigned old = atomicOr(&bm2[d >> 5], bit);
            if (!(old & bit)) deg[d] = 0;
        }
    }
    if (i < E4) {
        int4 d4 = ((const int4*)dst)[i];
        int dd[4] = {d4.x, d4.y, d4.z, d4.w};
#pragma unroll
        for (int k = 0; k < 4; ++k) {
            int d = dd[k];
            if ((bm1[d >> 5] >> (d & 31)) & 1u) {
                int s = src[i * 4 + k];
                int p = atomicAdd(&cnts[2], 1);
                if (p < L2CAP)
                    L2[p] = ((unsigned long long)(unsigned)d << 32) | (unsigned)s;
                unsigned bit = 1u << (s & 31);
                unsigned old = atomicOr(&bm2[s >> 5], bit);
                if (!(old & bit)) deg[s] = 0;
            }
        }
    }
    if (i == 0) {
        for (int e = E4 * 4; e < E; ++e) {
            int d = dst[e];
            if ((bm1[d >> 5] >> (d & 31)) & 1u) {
                int s = src[e];
                int p = atomicAdd(&cnts[2], 1);
                if (p < L2CAP)
                    L2[p] = ((unsigned long long)(unsigned)d << 32) | (unsigned)s;
                unsigned bit = 1u << (s & 31);
                unsigned old = atomicOr(&bm2[s >> 5], bit);
                if (!(old & bit)) deg[s] = 0;
            }
        }
    }
}

__global__ __launch_bounds__(256)
void k_pass3f(const float* __restrict__ x, const int* __restrict__ dst,
              int E4, int E, int n,
              const unsigned* __restrict__ bm2, int* __restrict__ deg,
              int* __restrict__ cnts, const int* __restrict__ S1,
              const int* __restrict__ Dlist,
              const unsigned long long* __restrict__ L2,
              const float* __restrict__ W1, const float* __restrict__ b1,
              const float* __restrict__ W2, const float* __restrict__ b2,
              const float* __restrict__ Wfc, const float* __restrict__ bfc,
              float* __restrict__ out) {
    const int tid = threadIdx.x;
    const int tgt = n - 1;

    // --- scan phase: identical to round-0 pass3 (no preamble, no fences) ---
    int i = blockIdx.x * blockDim.x + tid;
    if (i < E4) {
        int4 d4 = ((const int4*)dst)[i];
        int dd[4] = {d4.x, d4.y, d4.z, d4.w};
#pragma unroll
        for (int k = 0; k < 4; ++k) {
            int d = dd[k];
            if ((bm2[d >> 5] >> (d & 31)) & 1u) atomicAdd(&deg[d], 1);
        }
    }
    if (i == 0) {
        for (int e = E4 * 4; e < E; ++e) {
            int d = dst[e];
            if ((bm2[d >> 5] >> (d & 31)) & 1u) atomicAdd(&deg[d], 1);
        }
    }

    // --- ticket: drain own atomics, one atomic per block. NO threadfence. ---
    __shared__ int sLast;
    asm volatile("s_waitcnt vmcnt(0)" ::: "memory");
    __syncthreads();
    if (tid == 0)
        sLast = (atomicAdd(&cnts[3], 1) == (int)gridDim.x - 1) ? 1 : 0;
    __syncthreads();
    if (!sLast) return;

    // --- epilogue (last block only): round-0 k_final, deg via atomic reads ---
    __shared__ int hKey[HASHSZ];
    __shared__ int hVal[HASHSZ];
    __shared__ int sD[DCAP];
    __shared__ float s1D[DCAP];
    __shared__ float gD[DCAP][8];
    __shared__ float sW1[16], sb1[16], sW2[128], agg[8];

    int cnt1 = cnts[0]; if (cnt1 > S1CAP) cnt1 = S1CAP;
    int cntD = cnts[1]; if (cntD > DCAP) cntD = DCAP;
    int cnt2 = cnts[2]; if (cnt2 > L2CAP) cnt2 = L2CAP;

    for (int j = tid; j < HASHSZ; j += 256) hKey[j] = -1;
    for (int j = tid; j < cntD; j += 256) { sD[j] = Dlist[j]; s1D[j] = 0.f; }
    if (tid < 16) { sW1[tid] = W1[tid]; sb1[tid] = b1[tid]; }
    if (tid < 128) sW2[tid] = W2[tid];
    if (tid < 8) agg[tid] = 0.f;
    __syncthreads();
    // hash d -> index
    for (int j = tid; j < cntD; j += 256) {
        int d = sD[j];
        int h = d & (HASHSZ - 1);
        while (true) {
            int prev = atomicCAS(&hKey[h], -1, d);
            if (prev == -1 || prev == d) { hVal[h] = j; break; }
            h = (h + 1) & (HASHSZ - 1);
        }
    }
    __syncthreads();
    // per-edge messages -> LDS bins (deg written this kernel -> atomic reads)
    for (int e = tid; e < cnt2; e += 256) {
        unsigned long long v = L2[e];
        int s = (int)(v & 0xffffffffu);
        int d = (int)(v >> 32);
        int ds = atomicOr(&deg[s], 0);
        float msg = x[s] * rsqrtf((float)(ds + 1));
        int h = d & (HASHSZ - 1);
        while (hKey[h] != d) h = (h + 1) & (HASHSZ - 1);
        atomicAdd(&s1D[hVal[h]], msg);
    }
    __syncthreads();
    // per-D-node: h1 -> g row (g = dinv_src * (h1 @ W2))
    for (int di = tid; di < cntD; di += 256) {
        int d = sD[di];
        int dd = atomicOr(&deg[d], 0);
        float dv = rsqrtf((float)(dd + 1));
        float t = dv * (s1D[di] + x[d] * dv);   // + self-loop term
        float g8[8] = {0, 0, 0, 0, 0, 0, 0, 0};
#pragma unroll
        for (int c = 0; c < 16; ++c) {
            float h1 = fmaxf(fmaf(t, sW1[c], sb1[c]), 0.f);
#pragma unroll
            for (int j = 0; j < 8; ++j) g8[j] = fmaf(h1, sW2[c * 8 + j], g8[j]);
        }
#pragma unroll
        for (int j = 0; j < 8; ++j) gD[di][j] = dv * g8[j];
    }
    __syncthreads();
    // layer-2 aggregation at tgt over the S1 multiset
    for (int idx = tid; idx < cnt1 * 8; idx += 256) {
        int p = idx >> 3, j = idx & 7;
        int s = S1[p];
        int h = s & (HASHSZ - 1);
        while (hKey[h] != s) h = (h + 1) & (HASHSZ - 1);
        atomicAdd(&agg[j], gD[hVal[h]][j]);
    }
    __syncthreads();
    if (tid == 0) {
        int h = tgt & (HASHSZ - 1);
        while (hKey[h] != tgt) h = (h + 1) & (HASHSZ - 1);
        int it = hVal[h];
        int dt = atomicOr(&deg[tgt], 0);
        float dv = rsqrtf((float)(dt + 1));
        float o = 0.f;
#pragma unroll
        for (int j = 0; j < 8; ++j)
            o += fmaxf(fmaf(dv, agg[j] + gD[it][j], b2[j]), 0.f) * Wfc[j];
        out[0] = o + bfc[0];
    }
}

extern "C" void kernel_launch(void* const* d_in, const int* in_sizes, int n_in,
                              void* d_out, int out_size, void* d_ws, size_t ws_size,
                              hipStream_t stream) {
    const float* x   = (const float*)d_in[0];
    const int*   ei  = (const int*)d_in[1];
    const float* W1  = (const float*)d_in[2];
    const float* b1  = (const float*)d_in[3];
    const float* W2  = (const float*)d_in[4];
    const float* b2  = (const float*)d_in[5];
    const float* Wfc = (const float*)d_in[6];
    const float* bfc = (const float*)d_in[7];
    float* out = (float*)d_out;

    int n = in_sizes[0];
    int E = in_sizes[1] / 2;
    const int* src = ei;
    const int* dst = ei + E;

    auto align16 = [](size_t v) { return (v + 15) & ~(size_t)15; };
    size_t bmBytes = align16(((size_t)(n + 31) / 32) * 4);
    char* ws = (char*)d_ws;
    size_t off = 0;
    unsigned* bm1   = (unsigned*)(ws + off); off += bmBytes;
    unsigned* bm2   = (unsigned*)(ws + off); off += bmBytes;
    int*      cnts  = (int*)(ws + off);      off += 64;
    size_t zeroBytes = off;                  // bm1 + bm2 + cnts (~25KB)
    int*      deg   = (int*)(ws + off);      off += align16((size_t)n * 4);
    int*      S1    = (int*)(ws + off);      off += S1CAP * 4;
    int*      Dlist = (int*)(ws + off);      off += align16(DCAP * 4);
    unsigned long long* L2 = (unsigned long long*)(ws + off); off += (size_t)L2CAP * 8;

    hipMemsetAsync(d_ws, 0, zeroBytes, stream);

    int E4 = E >> 2;
    int bE4 = (E4 + 255) / 256;

    k_pass1<<<bE4, 256, 0, stream>>>(src, dst, E4, E, n, cnts, S1, bm1, Dlist);
    k_pass2<<<bE4, 256, 0, stream>>>(src, dst, E4, E, bm1, cnts, L2, bm2, deg, Dlist);
    k_pass3f<<<bE4, 256, 0, stream>>>(x, dst, E4, E, n, bm2, deg, cnts, S1,
                                      Dlist, L2, W1, b1, W2, b2, Wfc, bfc, out);
}

// Round 3
// 121.130 us; speedup vs baseline: 4.2012x; 1.5559x over previous
//
#include <hip/hip_runtime.h>

// Backward slice from the single output node n-1:
//   D = {n-1} U in-neighbors(n-1) (~34 nodes); layer-2 agg needs only edges
//   into D (~1100); deg needed only for their sources U D (~1135 nodes).
//
// Round-8: round-7's ticket worked (correct, fence-free) but 3125
// same-address device atomicAdds serialized at ~26ns each = 80us. Fix:
//   - all scan kernels: 768 blocks, grid-stride (4x less dispatch ramp,
//     still saturates HBM: 196k threads x 16B in flight)
//   - two-level ticket: 16 sub-counters on separate 128B lines (48 blocks
//     each, parallel across L2 atomic units), sub-winners escalate to root.
//     Ticket tail ~1-2us instead of 80.
// Dispatches: memset(~29KB) + pass1 + pass2 + pass3f.

#define S1CAP 2048
#define DCAP  192
#define L2CAP 65536
#define HASHSZ 512
#define GRID 768
#define NSUB 16
// cnts[0]=S1 count, [1]=D count, [2]=L2 count
// cnts[16 + sub*32] = sub-tickets (128B apart), cnts[16 + NSUB*32] = root

__global__ __launch_bounds__(256)
void k_pass1(const int* __restrict__ src, const int* __restrict__ dst,
             int E4, int E, int n, int* __restrict__ cnts,
             int* __restrict__ S1, unsigned* __restrict__ bm1,
             int* __restrict__ Dlist) {
    int gid = blockIdx.x * 256 + threadIdx.x;
    const int stride = GRID * 256;
    const int tgt = n - 1;
    for (int j = gid; j < E4; j += stride) {
        int4 d4 = ((const int4*)dst)[j];
        int dd[4] = {d4.x, d4.y, d4.z, d4.w};
#pragma unroll
        for (int k = 0; k < 4; ++k) {
            if (dd[k] == tgt) {
                int s = src[j * 4 + k];
                int p = atomicAdd(&cnts[0], 1);
                if (p < S1CAP) S1[p] = s;
                unsigned bit = 1u << (s & 31);
                unsigned old = atomicOr(&bm1[s >> 5], bit);
                if (!(old & bit)) {
                    int q = atomicAdd(&cnts[1], 1);
                    if (q < DCAP) Dlist[q] = s;
                }
            }
        }
    }
    if (gid == 0) {
        for (int e = E4 * 4; e < E; ++e) {
            if (dst[e] == tgt) {
                int s = src[e];
                int p = atomicAdd(&cnts[0], 1);
                if (p < S1CAP) S1[p] = s;
                unsigned bit = 1u << (s & 31);
                unsigned old = atomicOr(&bm1[s >> 5], bit);
                if (!(old & bit)) {
                    int q = atomicAdd(&cnts[1], 1);
                    if (q < DCAP) Dlist[q] = s;
                }
            }
        }
        // tgt itself is in D (self-loop)
        unsigned bit = 1u << (tgt & 31);
        unsigned old = atomicOr(&bm1[tgt >> 5], bit);
        if (!(old & bit)) {
            int q = atomicAdd(&cnts[1], 1);
            if (q < DCAP) Dlist[q] = tgt;
        }
    }
}

__global__ __launch_bounds__(256)
void k_pass2(const int* __restrict__ src, const int* __restrict__ dst,
             int E4, int E, const unsigned* __restrict__ bm1,
             int* __restrict__ cnts, unsigned long long* __restrict__ L2,
             unsigned* __restrict__ bm2, int* __restrict__ deg,
             const int* __restrict__ Dlist) {
    int gid = blockIdx.x * 256 + threadIdx.x;
    const int stride = GRID * 256;
    // D itself into bm2 (lazy deg zero)
    if (gid < DCAP) {
        int cntD = cnts[1]; if (cntD > DCAP) cntD = DCAP;
        if (gid < cntD) {
            int d = Dlist[gid];
            unsigned bit = 1u << (d & 31);
            unsigned old = atomicOr(&bm2[d >> 5], bit);
            if (!(old & bit)) deg[d] = 0;
        }
    }
    for (int j = gid; j < E4; j += stride) {
        int4 d4 = ((const int4*)dst)[j];
        int dd[4] = {d4.x, d4.y, d4.z, d4.w};
#pragma unroll
        for (int k = 0; k < 4; ++k) {
            int d = dd[k];
            if ((bm1[d >> 5] >> (d & 31)) & 1u) {
                int s = src[j * 4 + k];
                int p = atomicAdd(&cnts[2], 1);
                if (p < L2CAP)
                    L2[p] = ((unsigned long long)(unsigned)d << 32) | (unsigned)s;
                unsigned bit = 1u << (s & 31);
                unsigned old = atomicOr(&bm2[s >> 5], bit);
                if (!(old & bit)) deg[s] = 0;
            }
        }
    }
    if (gid == 0) {
        for (int e = E4 * 4; e < E; ++e) {
            int d = dst[e];
            if ((bm1[d >> 5] >> (d & 31)) & 1u) {
                int s = src[e];
                int p = atomicAdd(&cnts[2], 1);
                if (p < L2CAP)
                    L2[p] = ((unsigned long long)(unsigned)d << 32) | (unsigned)s;
                unsigned bit = 1u << (s & 31);
                unsigned old = atomicOr(&bm2[s >> 5], bit);
                if (!(old & bit)) deg[s] = 0;
            }
        }
    }
}

__global__ __launch_bounds__(256)
void k_pass3f(const float* __restrict__ x, const int* __restrict__ dst,
              int E4, int E, int n,
              const unsigned* __restrict__ bm2, int* __restrict__ deg,
              int* __restrict__ cnts, const int* __restrict__ S1,
              const int* __restrict__ Dlist,
              const unsigned long long* __restrict__ L2,
              const float* __restrict__ W1, const float* __restrict__ b1,
              const float* __restrict__ W2, const float* __restrict__ b2,
              const float* __restrict__ Wfc, const float* __restrict__ bfc,
              float* __restrict__ out) {
    const int tid = threadIdx.x;
    const int tgt = n - 1;

    // --- scan phase: bm2-filtered deg histogram (grid-stride) ---
    int gid = blockIdx.x * 256 + tid;
    const int stride = GRID * 256;
    for (int j = gid; j < E4; j += stride) {
        int4 d4 = ((const int4*)dst)[j];
        int dd[4] = {d4.x, d4.y, d4.z, d4.w};
#pragma unroll
        for (int k = 0; k < 4; ++k) {
            int d = dd[k];
            if ((bm2[d >> 5] >> (d & 31)) & 1u) atomicAdd(&deg[d], 1);
        }
    }
    if (gid == 0) {
        for (int e = E4 * 4; e < E; ++e) {
            int d = dst[e];
            if ((bm2[d >> 5] >> (d & 31)) & 1u) atomicAdd(&deg[d], 1);
        }
    }

    // --- two-level ticket: drain own atomics, then sub -> root. No fences. --
    __shared__ int sLast;
    asm volatile("s_waitcnt vmcnt(0)" ::: "memory");
    __syncthreads();
    if (tid == 0) {
        int last = 0;
        int sub = blockIdx.x % NSUB;               // GRID % NSUB == 0
        int quota = GRID / NSUB;
        int so = atomicAdd(&cnts[16 + sub * 32], 1);
        if (so == quota - 1) {
            int ro = atomicAdd(&cnts[16 + NSUB * 32], 1);
            if (ro == NSUB - 1) last = 1;
        }
        sLast = last;
    }
    __syncthreads();
    if (!sLast) return;

    // --- epilogue (last block only): deg via atomic reads (LLC-coherent) ---
    __shared__ int hKey[HASHSZ];
    __shared__ int hVal[HASHSZ];
    __shared__ int sD[DCAP];
    __shared__ float s1D[DCAP];
    __shared__ float gD[DCAP][8];
    __shared__ float sW1[16], sb1[16], sW2[128], agg[8];

    int cnt1 = cnts[0]; if (cnt1 > S1CAP) cnt1 = S1CAP;
    int cntD = cnts[1]; if (cntD > DCAP) cntD = DCAP;
    int cnt2 = cnts[2]; if (cnt2 > L2CAP) cnt2 = L2CAP;

    for (int j = tid; j < HASHSZ; j += 256) hKey[j] = -1;
    for (int j = tid; j < cntD; j += 256) { sD[j] = Dlist[j]; s1D[j] = 0.f; }
    if (tid < 16) { sW1[tid] = W1[tid]; sb1[tid] = b1[tid]; }
    if (tid < 128) sW2[tid] = W2[tid];
    if (tid < 8) agg[tid] = 0.f;
    __syncthreads();
    // hash d -> index
    for (int j = tid; j < cntD; j += 256) {
        int d = sD[j];
        int h = d & (HASHSZ - 1);
        while (true) {
            int prev = atomicCAS(&hKey[h], -1, d);
            if (prev == -1 || prev == d) { hVal[h] = j; break; }
            h = (h + 1) & (HASHSZ - 1);
        }
    }
    __syncthreads();
    // per-edge messages -> LDS bins
    for (int e = tid; e < cnt2; e += 256) {
        unsigned long long v = L2[e];
        int s = (int)(v & 0xffffffffu);
        int d = (int)(v >> 32);
        int ds = atomicOr(&deg[s], 0);
        float msg = x[s] * rsqrtf((float)(ds + 1));
        int h = d & (HASHSZ - 1);
        while (hKey[h] != d) h = (h + 1) & (HASHSZ - 1);
        atomicAdd(&s1D[hVal[h]], msg);
    }
    __syncthreads();
    // per-D-node: h1 -> g row (g = dinv_src * (h1 @ W2))
    for (int di = tid; di < cntD; di += 256) {
        int d = sD[di];
        int dd = atomicOr(&deg[d], 0);
        float dv = rsqrtf((float)(dd + 1));
        float t = dv * (s1D[di] + x[d] * dv);   // + self-loop term
        float g8[8] = {0, 0, 0, 0, 0, 0, 0, 0};
#pragma unroll
        for (int c = 0; c < 16; ++c) {
            float h1 = fmaxf(fmaf(t, sW1[c], sb1[c]), 0.f);
#pragma unroll
            for (int j = 0; j < 8; ++j) g8[j] = fmaf(h1, sW2[c * 8 + j], g8[j]);
        }
#pragma unroll
        for (int j = 0; j < 8; ++j) gD[di][j] = dv * g8[j];
    }
    __syncthreads();
    // layer-2 aggregation at tgt over the S1 multiset
    for (int idx = tid; idx < cnt1 * 8; idx += 256) {
        int p = idx >> 3, j = idx & 7;
        int s = S1[p];
        int h = s & (HASHSZ - 1);
        while (hKey[h] != s) h = (h + 1) & (HASHSZ - 1);
        atomicAdd(&agg[j], gD[hVal[h]][j]);
    }
    __syncthreads();
    if (tid == 0) {
        int h = tgt & (HASHSZ - 1);
        while (hKey[h] != tgt) h = (h + 1) & (HASHSZ - 1);
        int it = hVal[h];
        int dt = atomicOr(&deg[tgt], 0);
        float dv = rsqrtf((float)(dt + 1));
        float o = 0.f;
#pragma unroll
        for (int j = 0; j < 8; ++j)
            o += fmaxf(fmaf(dv, agg[j] + gD[it][j], b2[j]), 0.f) * Wfc[j];
        out[0] = o + bfc[0];
    }
}

extern "C" void kernel_launch(void* const* d_in, const int* in_sizes, int n_in,
                              void* d_out, int out_size, void* d_ws, size_t ws_size,
                              hipStream_t stream) {
    const float* x   = (const float*)d_in[0];
    const int*   ei  = (const int*)d_in[1];
    const float* W1  = (const float*)d_in[2];
    const float* b1  = (const float*)d_in[3];
    const float* W2  = (const float*)d_in[4];
    const float* b2  = (const float*)d_in[5];
    const float* Wfc = (const float*)d_in[6];
    const float* bfc = (const float*)d_in[7];
    float* out = (float*)d_out;

    int n = in_sizes[0];
    int E = in_sizes[1] / 2;
    const int* src = ei;
    const int* dst = ei + E;

    auto align16 = [](size_t v) { return (v + 15) & ~(size_t)15; };
    size_t bmBytes = align16(((size_t)(n + 31) / 32) * 4);
    char* ws = (char*)d_ws;
    size_t off = 0;
    unsigned* bm1   = (unsigned*)(ws + off); off += bmBytes;
    unsigned* bm2   = (unsigned*)(ws + off); off += bmBytes;
    int*      cnts  = (int*)(ws + off);      off += 4096;  // cnts + tickets
    size_t zeroBytes = off;                  // bm1 + bm2 + cnts/tickets (~29KB)
    int*      deg   = (int*)(ws + off);      off += align16((size_t)n * 4);
    int*      S1    = (int*)(ws + off);      off += S1CAP * 4;
    int*      Dlist = (int*)(ws + off);      off += align16(DCAP * 4);
    unsigned long long* L2 = (unsigned long long*)(ws + off); off += (size_t)L2CAP * 8;

    hipMemsetAsync(d_ws, 0, zeroBytes, stream);

    int E4 = E >> 2;

    k_pass1<<<GRID, 256, 0, stream>>>(src, dst, E4, E, n, cnts, S1, bm1, Dlist);
    k_pass2<<<GRID, 256, 0, stream>>>(src, dst, E4, E, bm1, cnts, L2, bm2, deg, Dlist);
    k_pass3f<<<GRID, 256, 0, stream>>>(x, dst, E4, E, n, bm2, deg, cnts, S1,
                                       Dlist, L2, W1, b1, W2, b2, Wfc, bfc, out);
}